// Round 9
// baseline (1637.552 us; speedup 1.0000x reference)
//
#include <hip/hip_runtime.h>
#include <math.h>

#define NN 50000
#define NE 200000
#define NH 4
#define NG 100
#define EPSBN 1e-5f
#define SLOPE 0.2f

typedef __attribute__((ext_vector_type(8))) short bf16x8;
typedef __attribute__((ext_vector_type(4))) float f32x4;

union U8 { bf16x8 v; uint4 q; unsigned w[4]; };

__device__ __forceinline__ unsigned short f2bf(float f) {
    unsigned u = __float_as_uint(f);
    unsigned r = (u + 0x7fffu + ((u >> 16) & 1u)) >> 16;   // RNE
    return (unsigned short)r;
}
__device__ __forceinline__ float bf2f(unsigned short s) {
    return __uint_as_float(((unsigned)s) << 16);
}

__global__ void fill_val(float* p, int n, float v) {
    int i = blockIdx.x * 256 + threadIdx.x;
    if (i < n) p[i] = v;
}

// ================= weight prep: fragment-tiled split panels =================
// Panel [512 cols][K k] -> short idx: ((n>>4)*(K/32) + (k>>5))*512
//                                    + (((k>>3)&3)*16 + (n&15))*8 + (k&7)
// GEMM lane l reads shorts [l*8, l*8+8) of tile (nt,kt): coalesced 1 KB/wave.

// L1 (per head h, K=256): element = (n<256?Wl1:Wr1)[k][h*256+(n&255)]; W1 [256,1024]
__global__ void wprep1t(const float* __restrict__ Wl, const float* __restrict__ Wr,
                        unsigned short* __restrict__ Bh, unsigned short* __restrict__ Bl) {
    int idx = blockIdx.x * 256 + threadIdx.x;   // 524288
    int n = idx & 511, k = (idx >> 9) & 255, h = idx >> 17;
    const float* W = (n < 256) ? Wl : Wr;
    float w = W[(size_t)k * 1024 + h * 256 + (n & 255)];
    size_t dst = (size_t)h * 131072 + (((size_t)(n >> 4) * 8 + (k >> 5)) << 9)
               + ((((k >> 3) & 3) << 4) + (n & 15)) * 8 + (k & 7);
    unsigned u = __float_as_uint(w);
    Bh[dst] = (unsigned short)(u >> 16);                       // trunc hi
    Bl[dst] = f2bf(w - __uint_as_float(u & 0xFFFF0000u));      // RNE lo
}
// L2 (K=1024): element = (n<256?Wl2:Wr2)[k][n&255]; W2 [1024,256]
__global__ void wprep2t(const float* __restrict__ Wl, const float* __restrict__ Wr,
                        unsigned short* __restrict__ Bh, unsigned short* __restrict__ Bl) {
    int idx = blockIdx.x * 256 + threadIdx.x;   // 524288
    int n = idx >> 10, k = idx & 1023;
    const float* W = (n < 256) ? Wl : Wr;
    float w = W[(size_t)k * 256 + (n & 255)];
    size_t dst = (((size_t)(n >> 4) * 32 + (k >> 5)) << 9)
               + ((((k >> 3) & 3) << 4) + (n & 15)) * 8 + (k & 7);
    unsigned u = __float_as_uint(w);
    Bh[dst] = (unsigned short)(u >> 16);
    Bl[dst] = f2bf(w - __uint_as_float(u & 0xFFFF0000u));
}

// ================= B-hi-in-LDS split-bf16 MFMA GEMM =================
// C[M,512] = A[M,K] @ B[512,K]^T + bias.  Block = 256 thr = 4 waves; 256 rows x
// 64 cols per block; wave w: rows [m0+64w,+64) (4 m-frags) x 4 n-frags.
// MODE 0: A f32, split in-reg, 3 passes (AhBh+AlBh+AhBl), K=256.
// MODE 1: A bf16-hi shorts, 2 passes (AhBh+AhBl), K=1024 (4 LDS chunks).
// B-hi chunk (32 KB) in LDS; B-lo streamed from global (L2-resident).
// grid (row-tiles, 8 slices): same-row blocks land on 2 XCDs -> A L2-shared.
template<int MODE>
__launch_bounds__(256, 4)
__global__ void gemm_bs(const float* __restrict__ Af,
                        const unsigned short* __restrict__ A2, int lda,
                        const unsigned short* __restrict__ Bh,
                        const unsigned short* __restrict__ Bl, int KT,
                        const float* __restrict__ bL, const float* __restrict__ bR,
                        float* __restrict__ C, int M) {
    __shared__ unsigned short BsH[16384];   // 32 KB: [4nt][8kt][512]
    const int tid = threadIdx.x;
    const int lane = tid & 63, w = tid >> 6;
    const int m0 = blockIdx.x * 256;
    const int slice = blockIdx.y;
    const int r15 = lane & 15, kq = lane >> 4;
    const size_t sliceBase = (size_t)slice * 4 * KT * 64;   // uint4 units

    f32x4 acc[4][4];
#pragma unroll
    for (int m = 0; m < 4; ++m)
#pragma unroll
        for (int n = 0; n < 4; ++n) acc[m][n] = (f32x4){0.f, 0.f, 0.f, 0.f};

    int rowm[4];
#pragma unroll
    for (int m = 0; m < 4; ++m) {
        int row = m0 + w * 64 + m * 16 + r15;
        rowm[m] = row < M ? row : M - 1;
    }

    const int nchunks = KT / 8;
    for (int kc = 0; kc < nchunks; ++kc) {
        // ---- fill B-hi chunk into LDS (2048 uint4) ----
        {
            const uint4* g = (const uint4*)Bh + sliceBase;
            uint4* l = (uint4*)BsH;
#pragma unroll
            for (int i = 0; i < 8; ++i) {
                int u = i * 256 + tid;
                int nt = u >> 9, rem = u & 511;
                int ktl = rem >> 6, j = u & 63;
                l[u] = g[((size_t)nt * KT + kc * 8 + ktl) * 64 + j];
            }
        }
        __syncthreads();

#pragma unroll
        for (int ktl = 0; ktl < 8; ++ktl) {
            const int kt = kc * 8 + ktl;
            bf16x8 ah[4], al[4];
            if (MODE == 0) {
#pragma unroll
                for (int m = 0; m < 4; ++m) {
                    const float* xp = Af + (size_t)rowm[m] * lda + kt * 32 + kq * 8;
                    float vv[8];
                    *(float4*)&vv[0] = *(const float4*)xp;
                    *(float4*)&vv[4] = *(const float4*)(xp + 4);
                    U8 uh, ul;
#pragma unroll
                    for (int j = 0; j < 4; ++j) {
                        float a0 = vv[2 * j], a1 = vv[2 * j + 1];
                        unsigned u0 = __float_as_uint(a0), u1 = __float_as_uint(a1);
                        uh.w[j] = (u0 >> 16) | (u1 & 0xFFFF0000u);
                        float l0 = a0 - __uint_as_float(u0 & 0xFFFF0000u);
                        float l1 = a1 - __uint_as_float(u1 & 0xFFFF0000u);
                        ul.w[j] = (unsigned)f2bf(l0) | ((unsigned)f2bf(l1) << 16);
                    }
                    ah[m] = uh.v; al[m] = ul.v;
                }
            } else {
#pragma unroll
                for (int m = 0; m < 4; ++m)
                    ah[m] = *(const bf16x8*)(A2 + (size_t)rowm[m] * lda + kt * 32 + kq * 8);
            }
#pragma unroll
            for (int n = 0; n < 4; ++n) {
                bf16x8 bh = *(const bf16x8*)&BsH[(n * 8 + ktl) * 512 + lane * 8];
                bf16x8 bl = *(const bf16x8*)(Bl + (((size_t)(slice * 4 + n) * KT + kt) << 9)
                                              + lane * 8);
#pragma unroll
                for (int m = 0; m < 4; ++m) {
                    acc[m][n] = __builtin_amdgcn_mfma_f32_16x16x32_bf16(
                        ah[m], bh, acc[m][n], 0, 0, 0);
                    if (MODE == 0)
                        acc[m][n] = __builtin_amdgcn_mfma_f32_16x16x32_bf16(
                            al[m], bh, acc[m][n], 0, 0, 0);
                    acc[m][n] = __builtin_amdgcn_mfma_f32_16x16x32_bf16(
                        ah[m], bl, acc[m][n], 0, 0, 0);
                }
            }
        }
        __syncthreads();
    }
    // ---- epilogue: C/D col=lane&15, row=(lane>>4)*4+reg (verified r4-8) ----
#pragma unroll
    for (int n = 0; n < 4; ++n) {
        int gcol = slice * 64 + n * 16 + r15;
        float bv = (gcol < 256) ? bL[gcol] : bR[gcol - 256];
#pragma unroll
        for (int m = 0; m < 4; ++m) {
#pragma unroll
            for (int r = 0; r < 4; ++r) {
                int grow = m0 + w * 64 + m * 16 + kq * 4 + r;
                if (grow < M)
                    C[(size_t)grow * 512 + gcol] = acc[m][n][r] + bv;
            }
        }
    }
}

// ================= CSR build over dst (verified r5-8) =================
__global__ void csr_count(const int* __restrict__ ei, int* __restrict__ cnt) {
    int e = blockIdx.x * 256 + threadIdx.x;
    if (e < NE) atomicAdd(&cnt[ei[NE + e]], 1);
}
__launch_bounds__(1024)
__global__ void csr_offsets(const int* __restrict__ cnt, int* __restrict__ off,
                            int* __restrict__ cursor) {
    __shared__ int s[1024];
    const int t = threadIdx.x;
    const int PER = 49;
    const int base = t * PER;
    int sum = 0;
    for (int i = 0; i < PER; ++i) {
        int idx = base + i;
        if (idx < NN) sum += cnt[idx];
    }
    s[t] = sum;
    __syncthreads();
    for (int d = 1; d < 1024; d <<= 1) {
        int v = (t >= d) ? s[t - d] : 0;
        __syncthreads();
        s[t] += v;
        __syncthreads();
    }
    int run = s[t] - sum;
    for (int i = 0; i < PER; ++i) {
        int idx = base + i;
        if (idx < NN) {
            off[idx] = run;
            cursor[idx] = run;
            run += cnt[idx];
            if (idx == NN - 1) off[NN] = run;
        }
    }
}
__global__ void csr_fill(const int* __restrict__ ei, int* __restrict__ cursor,
                         int* __restrict__ eidl) {
    int e = blockIdx.x * 256 + threadIdx.x;
    if (e < NE) {
        int d = ei[NE + e];
        int p = atomicAdd(&cursor[d], 1);
        eidl[p] = e;
    }
}

// ---------- per-edge logit partial (verbatim r6) ----------
__device__ __forceinline__ float edge_part(const float4& l, const float4& r,
                                           const float* ev, const float (*rW)[4],
                                           const float4& attv) {
    const float* lp = &l.x; const float* rp = &r.x; const float* ap = &attv.x;
    float part = 0.f;
#pragma unroll
    for (int j = 0; j < 4; ++j) {
        float ecf = 0.f;
#pragma unroll
        for (int d = 0; d < 12; ++d) ecf = fmaf(ev[d], rW[d][j], ecf);
        float mv = lp[j] + rp[j] + ecf;
        mv = mv > 0.f ? mv : SLOPE * mv;
        part = fmaf(mv, ap[j], part);
    }
    return part;
}

// ---------- fused node pass (r6 structure): 4 nodes/block, wave/node ----------
// OUTHI: write h1 bf16-hi into h1hi[n*1024 + hcol + cf] (L1).
// else: f32 in-place over own row's xr half (L2).
template<int NHEADS, bool OUTHI>
__launch_bounds__(256)
__global__ void node_fused(float* __restrict__ xlr,
                           const int* __restrict__ off, const int* __restrict__ eidl,
                           const int* __restrict__ ei, const float* __restrict__ ea,
                           const float* __restrict__ We, int ldwe,
                           const float* __restrict__ att,
                           const float* __restrict__ bias, const float* __restrict__ gam,
                           const float* __restrict__ bet, const float* __restrict__ mu,
                           const float* __restrict__ var,
                           unsigned short* __restrict__ h1hi, int hcol) {
    const int n = blockIdx.x * 4 + (threadIdx.x >> 6);
    const int lane = threadIdx.x & 63;
    const int cf = lane * 4;
    float rW[12][4];
#pragma unroll
    for (int d = 0; d < 12; ++d) {
        float4 w = *(const float4*)&We[(size_t)d * ldwe + cf];
        rW[d][0] = w.x; rW[d][1] = w.y; rW[d][2] = w.z; rW[d][3] = w.w;
    }
    const float4 attv = *(const float4*)&att[cf];
    float* xrow = xlr + (size_t)n * 512;
    const float4 xr4 = *(const float4*)(xrow + 256 + cf);
    float acc[4] = {0.f, 0.f, 0.f, 0.f};
    float den = 0.f;
    const int beg = off[n], end = off[n + 1];
    constexpr int RED = 64 / NHEADS;
    int k = beg;
    for (; k + 2 <= end; k += 2) {
        int e0 = eidl[k], e1 = eidl[k + 1];
        int s0 = ei[e0], s1 = ei[e1];
        float ev0[12], ev1[12];
        const float2* p0 = (const float2*)(ea + (size_t)e0 * 12);
        const float2* p1 = (const float2*)(ea + (size_t)e1 * 12);
#pragma unroll
        for (int d = 0; d < 6; ++d) {
            float2 a = p0[d], b = p1[d];
            ev0[2 * d] = a.x; ev0[2 * d + 1] = a.y;
            ev1[2 * d] = b.x; ev1[2 * d + 1] = b.y;
        }
        float4 l0 = *(const float4*)(xlr + (size_t)s0 * 512 + cf);
        float4 l1 = *(const float4*)(xlr + (size_t)s1 * 512 + cf);
        float pa = edge_part(l0, xr4, ev0, rW, attv);
        float pb = edge_part(l1, xr4, ev1, rW, attv);
#pragma unroll
        for (int o = RED / 2; o > 0; o >>= 1) {
            pa += __shfl_xor(pa, o);
            pb += __shfl_xor(pb, o);
        }
        float ex0 = __expf(pa), ex1 = __expf(pb);
        den += ex0 + ex1;
        const float* lp0 = &l0.x; const float* lp1 = &l1.x;
#pragma unroll
        for (int j = 0; j < 4; ++j)
            acc[j] = fmaf(ex0, lp0[j], fmaf(ex1, lp1[j], acc[j]));
    }
    if (k < end) {
        int e0 = eidl[k];
        int s0 = ei[e0];
        float ev0[12];
        const float2* p0 = (const float2*)(ea + (size_t)e0 * 12);
#pragma unroll
        for (int d = 0; d < 6; ++d) {
            float2 a = p0[d];
            ev0[2 * d] = a.x; ev0[2 * d + 1] = a.y;
        }
        float4 l0 = *(const float4*)(xlr + (size_t)s0 * 512 + cf);
        float pa = edge_part(l0, xr4, ev0, rW, attv);
#pragma unroll
        for (int o = RED / 2; o > 0; o >>= 1) pa += __shfl_xor(pa, o);
        float ex0 = __expf(pa);
        den += ex0;
        const float* lp0 = &l0.x;
#pragma unroll
        for (int j = 0; j < 4; ++j) acc[j] = fmaf(ex0, lp0[j], acc[j]);
    }
    const float inv = 1.f / (den + 1e-16f);
    float o[4];
#pragma unroll
    for (int j = 0; j < 4; ++j) {
        int c = cf + j;
        float t = fmaxf(acc[j] * inv + bias[c], 0.f);
        o[j] = (t - mu[c]) * rsqrtf(var[c] + EPSBN) * gam[c] + bet[c];
    }
    if (OUTHI) {
        ushort4 hv;
        hv.x = f2bf(o[0]); hv.y = f2bf(o[1]); hv.z = f2bf(o[2]); hv.w = f2bf(o[3]);
        *(ushort4*)(h1hi + (size_t)n * 1024 + hcol + cf) = hv;
    } else {
        *(float4*)(xrow + 256 + cf) = make_float4(o[0], o[1], o[2], o[3]);
    }
}

// ================= head MLP =================
__launch_bounds__(64)
__global__ void head_mlp(const float* __restrict__ h2, const int* __restrict__ n_nodes,
                         const float* __restrict__ Wf1, const float* __restrict__ bf1,
                         const float* __restrict__ Wf2, const float* __restrict__ bf2,
                         float* __restrict__ out) {
    const int g = blockIdx.x;
    const int t = threadIdx.x;
    int acc = 0;
    for (int i = t; i <= g; i += 64) acc += n_nodes[i];
#pragma unroll
    for (int off = 32; off > 0; off >>= 1) acc += __shfl_xor(acc, off);
    const int node = acc - 1;
    __shared__ float row[256];
    for (int i = t; i < 256; i += 64) row[i] = h2[(size_t)node * 512 + 256 + i];
    __syncthreads();
    float hid = bf1[t];
    for (int k = 0; k < 256; ++k) hid = fmaf(row[k], Wf1[k * 64 + t], hid);
    hid = fmaxf(hid, 0.f);
    float p = hid * Wf2[t];
#pragma unroll
    for (int off = 32; off > 0; off >>= 1) p += __shfl_xor(p, off);
    if (t == 0) out[g] = p + bf2[0];
}

extern "C" void kernel_launch(void* const* d_in, const int* in_sizes, int n_in,
                              void* d_out, int out_size, void* d_ws, size_t ws_size,
                              hipStream_t stream) {
    const float* x   = (const float*)d_in[0];
    const int*   ei  = (const int*)d_in[1];
    const float* ea  = (const float*)d_in[2];
    const int*   nnd = (const int*)d_in[3];
    const float* Wl1 = (const float*)d_in[4];
    const float* bl1 = (const float*)d_in[5];
    const float* Wr1 = (const float*)d_in[6];
    const float* br1 = (const float*)d_in[7];
    const float* We1 = (const float*)d_in[8];
    const float* att1= (const float*)d_in[9];
    const float* b1  = (const float*)d_in[10];
    const float* g1  = (const float*)d_in[11];
    const float* be1 = (const float*)d_in[12];
    const float* m1  = (const float*)d_in[13];
    const float* v1  = (const float*)d_in[14];
    const float* Wl2 = (const float*)d_in[15];
    const float* bl2 = (const float*)d_in[16];
    const float* Wr2 = (const float*)d_in[17];
    const float* br2 = (const float*)d_in[18];
    const float* We2 = (const float*)d_in[19];
    const float* att2= (const float*)d_in[20];
    const float* b2  = (const float*)d_in[21];
    const float* g2  = (const float*)d_in[22];
    const float* be2 = (const float*)d_in[23];
    const float* m2  = (const float*)d_in[24];
    const float* v2  = (const float*)d_in[25];
    const float* Wf1 = (const float*)d_in[26];
    const float* bf1 = (const float*)d_in[27];
    const float* Wf2 = (const float*)d_in[28];
    const float* bf2 = (const float*)d_in[29];
    float* out = (float*)d_out;

    // ---- workspace (~209.7 MB; proven >= 212.8 MB) ----
    const size_t XB  = (size_t)NN * 512 * 4;       // 102.4 MB panel
    const size_t HB  = (size_t)NN * 1024 * 2;      // 102.4 MB h1 bf16-hi
    const size_t WPB = (size_t)524288 * 2;         // 1 MB per split plane
    char* ws = (char*)d_ws;
    size_t off = 0;
    float* xlr  = (float*)(ws + off); off += XB;   // L1 panel; later xlr2 (L2 out)
    unsigned short* h1hi = (unsigned short*)(ws + off); off += HB;
    unsigned short* B1h = (unsigned short*)(ws + off); off += WPB;
    unsigned short* B1l = (unsigned short*)(ws + off); off += WPB;
    unsigned short* B2h = (unsigned short*)(ws + off); off += WPB;
    unsigned short* B2l = (unsigned short*)(ws + off); off += WPB;
    int* cnt    = (int*)(ws + off); off += (size_t)NN * 4;
    int* csroff = (int*)(ws + off); off += ((size_t)(NN + 1) * 4 + 15) & ~15ull;
    int* cursor = (int*)(ws + off); off += (size_t)NN * 4;
    int* eidl   = (int*)(ws + off); off += (size_t)NE * 4;
    if (ws_size < off) {
        fill_val<<<(out_size + 255) / 256, 256, 0, stream>>>(out, out_size, 1e30f);
        return;
    }
    float* xlr2 = xlr;   // alias: xlr dead after last node_l1

    // ---- CSR build (once) ----
    hipMemsetAsync(cnt, 0, (size_t)NN * 4, stream);
    csr_count<<<(NE + 255) / 256, 256, 0, stream>>>(ei, cnt);
    csr_offsets<<<1, 1024, 0, stream>>>(cnt, csroff, cursor);
    csr_fill<<<(NE + 255) / 256, 256, 0, stream>>>(ei, cursor, eidl);

    // ---- weight prep ----
    wprep1t<<<2048, 256, 0, stream>>>(Wl1, Wr1, B1h, B1l);
    wprep2t<<<2048, 256, 0, stream>>>(Wl2, Wr2, B2h, B2l);

    const dim3 gg((NN + 255) / 256, 8);   // (196 row-tiles, 8 slices): x fastest
    const int nodeBlocks = NN / 4;

    // ================= layer 1, per head =================
    for (int h = 0; h < NH; ++h) {
        gemm_bs<0><<<gg, 256, 0, stream>>>(
            x, nullptr, 256, B1h + (size_t)h * 131072, B1l + (size_t)h * 131072, 8,
            bl1 + h * 256, br1 + h * 256, xlr, NN);
        node_fused<1, true><<<nodeBlocks, 256, 0, stream>>>(
            xlr, csroff, eidl, ei, ea, We1 + h * 256, 1024, att1 + h * 256,
            b1 + h * 256, g1 + h * 256, be1 + h * 256, m1 + h * 256, v1 + h * 256,
            h1hi, h * 256);
    }

    // ================= layer 2: single K=1024 GEMM =================
    gemm_bs<1><<<gg, 256, 0, stream>>>(
        nullptr, h1hi, 1024, B2h, B2l, 32, bl2, br2, xlr2, NN);
    node_fused<4, false><<<nodeBlocks, 256, 0, stream>>>(
        xlr2, csroff, eidl, ei, ea, We2, 256, att2, b2, g2, be2, m2, v2,
        nullptr, 0);

    head_mlp<<<NG, 64, 0, stream>>>(xlr2, nnd, Wf1, bf1, Wf2, bf2, out);
}

// Round 10
// 1588.428 us; speedup vs baseline: 1.0309x; 1.0309x over previous
//
#include <hip/hip_runtime.h>
#include <math.h>

#define NN 50000
#define NE 200000
#define NH 4
#define NG 100
#define EPSBN 1e-5f
#define SLOPE 0.2f

typedef __attribute__((ext_vector_type(8))) short bf16x8;
typedef __attribute__((ext_vector_type(4))) float f32x4;

union U8 { bf16x8 v; uint4 q; unsigned w[4]; };

__device__ __forceinline__ unsigned short f2bf(float f) {
    unsigned u = __float_as_uint(f);
    unsigned r = (u + 0x7fffu + ((u >> 16) & 1u)) >> 16;   // RNE
    return (unsigned short)r;
}
__device__ __forceinline__ float bf2f(unsigned short s) {
    return __uint_as_float(((unsigned)s) << 16);
}

__global__ void fill_val(float* p, int n, float v) {
    int i = blockIdx.x * 256 + threadIdx.x;
    if (i < n) p[i] = v;
}

// ================= weight prep: fragment-tiled split panels (verbatim r9) =================
__global__ void wprep1t(const float* __restrict__ Wl, const float* __restrict__ Wr,
                        unsigned short* __restrict__ Bh, unsigned short* __restrict__ Bl) {
    int idx = blockIdx.x * 256 + threadIdx.x;   // 524288
    int n = idx & 511, k = (idx >> 9) & 255, h = idx >> 17;
    const float* W = (n < 256) ? Wl : Wr;
    float w = W[(size_t)k * 1024 + h * 256 + (n & 255)];
    size_t dst = (size_t)h * 131072 + (((size_t)(n >> 4) * 8 + (k >> 5)) << 9)
               + ((((k >> 3) & 3) << 4) + (n & 15)) * 8 + (k & 7);
    unsigned u = __float_as_uint(w);
    Bh[dst] = (unsigned short)(u >> 16);                       // trunc hi
    Bl[dst] = f2bf(w - __uint_as_float(u & 0xFFFF0000u));      // RNE lo
}
__global__ void wprep2t(const float* __restrict__ Wl, const float* __restrict__ Wr,
                        unsigned short* __restrict__ Bh, unsigned short* __restrict__ Bl) {
    int idx = blockIdx.x * 256 + threadIdx.x;   // 524288
    int n = idx >> 10, k = idx & 1023;
    const float* W = (n < 256) ? Wl : Wr;
    float w = W[(size_t)k * 256 + (n & 255)];
    size_t dst = (((size_t)(n >> 4) * 32 + (k >> 5)) << 9)
               + ((((k >> 3) & 3) << 4) + (n & 15)) * 8 + (k & 7);
    unsigned u = __float_as_uint(w);
    Bh[dst] = (unsigned short)(u >> 16);
    Bl[dst] = f2bf(w - __uint_as_float(u & 0xFFFF0000u));
}

// ================= B-hi-in-LDS split-bf16 MFMA GEMM (r9 + strip-clustered grid) =================
// 1D grid p in [0, 64*ceil(strips/8)): a=p>>6, slice=(p>>3)&7, strip r=8a+(p&7).
// All 8 slices of strip r at p==r (mod 8) -> same XCD + adjacent dispatch ->
// A strip fetched from HBM once, L2-served 7x. (r9 row-fastest grid: FETCH 374MB = 7.3x A.)
template<int MODE>
__launch_bounds__(256, 4)
__global__ void gemm_bs(const float* __restrict__ Af,
                        const unsigned short* __restrict__ A2, int lda,
                        const unsigned short* __restrict__ Bh,
                        const unsigned short* __restrict__ Bl, int KT,
                        const float* __restrict__ bL, const float* __restrict__ bR,
                        float* __restrict__ C, int M) {
    __shared__ unsigned short BsH[16384];   // 32 KB: [4nt][8kt][512]
    const int p = blockIdx.x;
    const int strip = ((p >> 6) << 3) + (p & 7);
    if (strip * 256 >= M) return;           // padded tail (whole block exits)
    const int slice = (p >> 3) & 7;
    const int m0 = strip * 256;
    const int tid = threadIdx.x;
    const int lane = tid & 63, w = tid >> 6;
    const int r15 = lane & 15, kq = lane >> 4;
    const size_t sliceBase = (size_t)slice * 4 * KT * 64;   // uint4 units

    f32x4 acc[4][4];
#pragma unroll
    for (int m = 0; m < 4; ++m)
#pragma unroll
        for (int n = 0; n < 4; ++n) acc[m][n] = (f32x4){0.f, 0.f, 0.f, 0.f};

    int rowm[4];
#pragma unroll
    for (int m = 0; m < 4; ++m) {
        int row = m0 + w * 64 + m * 16 + r15;
        rowm[m] = row < M ? row : M - 1;
    }

    const int nchunks = KT / 8;
    for (int kc = 0; kc < nchunks; ++kc) {
        // ---- fill B-hi chunk into LDS (2048 uint4) ----
        {
            const uint4* g = (const uint4*)Bh + sliceBase;
            uint4* l = (uint4*)BsH;
#pragma unroll
            for (int i = 0; i < 8; ++i) {
                int u = i * 256 + tid;
                int nt = u >> 9, rem = u & 511;
                int ktl = rem >> 6, j = u & 63;
                l[u] = g[((size_t)nt * KT + kc * 8 + ktl) * 64 + j];
            }
        }
        __syncthreads();

#pragma unroll
        for (int ktl = 0; ktl < 8; ++ktl) {
            const int kt = kc * 8 + ktl;
            bf16x8 ah[4], al[4];
            if (MODE == 0) {
#pragma unroll
                for (int m = 0; m < 4; ++m) {
                    const float* xp = Af + (size_t)rowm[m] * lda + kt * 32 + kq * 8;
                    float vv[8];
                    *(float4*)&vv[0] = *(const float4*)xp;
                    *(float4*)&vv[4] = *(const float4*)(xp + 4);
                    U8 uh, ul;
#pragma unroll
                    for (int j = 0; j < 4; ++j) {
                        float a0 = vv[2 * j], a1 = vv[2 * j + 1];
                        unsigned u0 = __float_as_uint(a0), u1 = __float_as_uint(a1);
                        uh.w[j] = (u0 >> 16) | (u1 & 0xFFFF0000u);
                        float l0 = a0 - __uint_as_float(u0 & 0xFFFF0000u);
                        float l1 = a1 - __uint_as_float(u1 & 0xFFFF0000u);
                        ul.w[j] = (unsigned)f2bf(l0) | ((unsigned)f2bf(l1) << 16);
                    }
                    ah[m] = uh.v; al[m] = ul.v;
                }
            } else {
#pragma unroll
                for (int m = 0; m < 4; ++m)
                    ah[m] = *(const bf16x8*)(A2 + (size_t)rowm[m] * lda + kt * 32 + kq * 8);
            }
#pragma unroll
            for (int n = 0; n < 4; ++n) {
                bf16x8 bh = *(const bf16x8*)&BsH[(n * 8 + ktl) * 512 + lane * 8];
                bf16x8 bl = *(const bf16x8*)(Bl + (((size_t)(slice * 4 + n) * KT + kt) << 9)
                                              + lane * 8);
#pragma unroll
                for (int m = 0; m < 4; ++m) {
                    acc[m][n] = __builtin_amdgcn_mfma_f32_16x16x32_bf16(
                        ah[m], bh, acc[m][n], 0, 0, 0);
                    if (MODE == 0)
                        acc[m][n] = __builtin_amdgcn_mfma_f32_16x16x32_bf16(
                            al[m], bh, acc[m][n], 0, 0, 0);
                    acc[m][n] = __builtin_amdgcn_mfma_f32_16x16x32_bf16(
                        ah[m], bl, acc[m][n], 0, 0, 0);
                }
            }
        }
        __syncthreads();
    }
    // ---- epilogue: C/D col=lane&15, row=(lane>>4)*4+reg (verified r4-9) ----
#pragma unroll
    for (int n = 0; n < 4; ++n) {
        int gcol = slice * 64 + n * 16 + r15;
        float bv = (gcol < 256) ? bL[gcol] : bR[gcol - 256];
#pragma unroll
        for (int m = 0; m < 4; ++m) {
#pragma unroll
            for (int r = 0; r < 4; ++r) {
                int grow = m0 + w * 64 + m * 16 + kq * 4 + r;
                if (grow < M)
                    C[(size_t)grow * 512 + gcol] = acc[m][n][r] + bv;
            }
        }
    }
}

// ================= CSR build over dst (verified r5-9) =================
__global__ void csr_count(const int* __restrict__ ei, int* __restrict__ cnt) {
    int e = blockIdx.x * 256 + threadIdx.x;
    if (e < NE) atomicAdd(&cnt[ei[NE + e]], 1);
}
__launch_bounds__(1024)
__global__ void csr_offsets(const int* __restrict__ cnt, int* __restrict__ off,
                            int* __restrict__ cursor) {
    __shared__ int s[1024];
    const int t = threadIdx.x;
    const int PER = 49;
    const int base = t * PER;
    int sum = 0;
    for (int i = 0; i < PER; ++i) {
        int idx = base + i;
        if (idx < NN) sum += cnt[idx];
    }
    s[t] = sum;
    __syncthreads();
    for (int d = 1; d < 1024; d <<= 1) {
        int v = (t >= d) ? s[t - d] : 0;
        __syncthreads();
        s[t] += v;
        __syncthreads();
    }
    int run = s[t] - sum;
    for (int i = 0; i < PER; ++i) {
        int idx = base + i;
        if (idx < NN) {
            off[idx] = run;
            cursor[idx] = run;
            run += cnt[idx];
            if (idx == NN - 1) off[NN] = run;
        }
    }
}
__global__ void csr_fill(const int* __restrict__ ei, int* __restrict__ cursor,
                         int* __restrict__ eidl) {
    int e = blockIdx.x * 256 + threadIdx.x;
    if (e < NE) {
        int d = ei[NE + e];
        int p = atomicAdd(&cursor[d], 1);
        eidl[p] = e;
    }
}

// ---------- per-edge logit partial (verbatim r6) ----------
__device__ __forceinline__ float edge_part(const float4& l, const float4& r,
                                           const float* ev, const float (*rW)[4],
                                           const float4& attv) {
    const float* lp = &l.x; const float* rp = &r.x; const float* ap = &attv.x;
    float part = 0.f;
#pragma unroll
    for (int j = 0; j < 4; ++j) {
        float ecf = 0.f;
#pragma unroll
        for (int d = 0; d < 12; ++d) ecf = fmaf(ev[d], rW[d][j], ecf);
        float mv = lp[j] + rp[j] + ecf;
        mv = mv > 0.f ? mv : SLOPE * mv;
        part = fmaf(mv, ap[j], part);
    }
    return part;
}

// ---------- fused node pass (verbatim r9) ----------
template<int NHEADS, bool OUTHI>
__launch_bounds__(256)
__global__ void node_fused(float* __restrict__ xlr,
                           const int* __restrict__ off, const int* __restrict__ eidl,
                           const int* __restrict__ ei, const float* __restrict__ ea,
                           const float* __restrict__ We, int ldwe,
                           const float* __restrict__ att,
                           const float* __restrict__ bias, const float* __restrict__ gam,
                           const float* __restrict__ bet, const float* __restrict__ mu,
                           const float* __restrict__ var,
                           unsigned short* __restrict__ h1hi, int hcol) {
    const int n = blockIdx.x * 4 + (threadIdx.x >> 6);
    const int lane = threadIdx.x & 63;
    const int cf = lane * 4;
    float rW[12][4];
#pragma unroll
    for (int d = 0; d < 12; ++d) {
        float4 w = *(const float4*)&We[(size_t)d * ldwe + cf];
        rW[d][0] = w.x; rW[d][1] = w.y; rW[d][2] = w.z; rW[d][3] = w.w;
    }
    const float4 attv = *(const float4*)&att[cf];
    float* xrow = xlr + (size_t)n * 512;
    const float4 xr4 = *(const float4*)(xrow + 256 + cf);
    float acc[4] = {0.f, 0.f, 0.f, 0.f};
    float den = 0.f;
    const int beg = off[n], end = off[n + 1];
    constexpr int RED = 64 / NHEADS;
    int k = beg;
    for (; k + 2 <= end; k += 2) {
        int e0 = eidl[k], e1 = eidl[k + 1];
        int s0 = ei[e0], s1 = ei[e1];
        float ev0[12], ev1[12];
        const float2* p0 = (const float2*)(ea + (size_t)e0 * 12);
        const float2* p1 = (const float2*)(ea + (size_t)e1 * 12);
#pragma unroll
        for (int d = 0; d < 6; ++d) {
            float2 a = p0[d], b = p1[d];
            ev0[2 * d] = a.x; ev0[2 * d + 1] = a.y;
            ev1[2 * d] = b.x; ev1[2 * d + 1] = b.y;
        }
        float4 l0 = *(const float4*)(xlr + (size_t)s0 * 512 + cf);
        float4 l1 = *(const float4*)(xlr + (size_t)s1 * 512 + cf);
        float pa = edge_part(l0, xr4, ev0, rW, attv);
        float pb = edge_part(l1, xr4, ev1, rW, attv);
#pragma unroll
        for (int o = RED / 2; o > 0; o >>= 1) {
            pa += __shfl_xor(pa, o);
            pb += __shfl_xor(pb, o);
        }
        float ex0 = __expf(pa), ex1 = __expf(pb);
        den += ex0 + ex1;
        const float* lp0 = &l0.x; const float* lp1 = &l1.x;
#pragma unroll
        for (int j = 0; j < 4; ++j)
            acc[j] = fmaf(ex0, lp0[j], fmaf(ex1, lp1[j], acc[j]));
    }
    if (k < end) {
        int e0 = eidl[k];
        int s0 = ei[e0];
        float ev0[12];
        const float2* p0 = (const float2*)(ea + (size_t)e0 * 12);
#pragma unroll
        for (int d = 0; d < 6; ++d) {
            float2 a = p0[d];
            ev0[2 * d] = a.x; ev0[2 * d + 1] = a.y;
        }
        float4 l0 = *(const float4*)(xlr + (size_t)s0 * 512 + cf);
        float pa = edge_part(l0, xr4, ev0, rW, attv);
#pragma unroll
        for (int o = RED / 2; o > 0; o >>= 1) pa += __shfl_xor(pa, o);
        float ex0 = __expf(pa);
        den += ex0;
        const float* lp0 = &l0.x;
#pragma unroll
        for (int j = 0; j < 4; ++j) acc[j] = fmaf(ex0, lp0[j], acc[j]);
    }
    const float inv = 1.f / (den + 1e-16f);
    float o[4];
#pragma unroll
    for (int j = 0; j < 4; ++j) {
        int c = cf + j;
        float t = fmaxf(acc[j] * inv + bias[c], 0.f);
        o[j] = (t - mu[c]) * rsqrtf(var[c] + EPSBN) * gam[c] + bet[c];
    }
    if (OUTHI) {
        ushort4 hv;
        hv.x = f2bf(o[0]); hv.y = f2bf(o[1]); hv.z = f2bf(o[2]); hv.w = f2bf(o[3]);
        *(ushort4*)(h1hi + (size_t)n * 1024 + hcol + cf) = hv;
    } else {
        *(float4*)(xrow + 256 + cf) = make_float4(o[0], o[1], o[2], o[3]);
    }
}

// ================= head MLP =================
__launch_bounds__(64)
__global__ void head_mlp(const float* __restrict__ h2, const int* __restrict__ n_nodes,
                         const float* __restrict__ Wf1, const float* __restrict__ bf1,
                         const float* __restrict__ Wf2, const float* __restrict__ bf2,
                         float* __restrict__ out) {
    const int g = blockIdx.x;
    const int t = threadIdx.x;
    int acc = 0;
    for (int i = t; i <= g; i += 64) acc += n_nodes[i];
#pragma unroll
    for (int off = 32; off > 0; off >>= 1) acc += __shfl_xor(acc, off);
    const int node = acc - 1;
    __shared__ float row[256];
    for (int i = t; i < 256; i += 64) row[i] = h2[(size_t)node * 512 + 256 + i];
    __syncthreads();
    float hid = bf1[t];
    for (int k = 0; k < 256; ++k) hid = fmaf(row[k], Wf1[k * 64 + t], hid);
    hid = fmaxf(hid, 0.f);
    float p = hid * Wf2[t];
#pragma unroll
    for (int off = 32; off > 0; off >>= 1) p += __shfl_xor(p, off);
    if (t == 0) out[g] = p + bf2[0];
}

extern "C" void kernel_launch(void* const* d_in, const int* in_sizes, int n_in,
                              void* d_out, int out_size, void* d_ws, size_t ws_size,
                              hipStream_t stream) {
    const float* x   = (const float*)d_in[0];
    const int*   ei  = (const int*)d_in[1];
    const float* ea  = (const float*)d_in[2];
    const int*   nnd = (const int*)d_in[3];
    const float* Wl1 = (const float*)d_in[4];
    const float* bl1 = (const float*)d_in[5];
    const float* Wr1 = (const float*)d_in[6];
    const float* br1 = (const float*)d_in[7];
    const float* We1 = (const float*)d_in[8];
    const float* att1= (const float*)d_in[9];
    const float* b1  = (const float*)d_in[10];
    const float* g1  = (const float*)d_in[11];
    const float* be1 = (const float*)d_in[12];
    const float* m1  = (const float*)d_in[13];
    const float* v1  = (const float*)d_in[14];
    const float* Wl2 = (const float*)d_in[15];
    const float* bl2 = (const float*)d_in[16];
    const float* Wr2 = (const float*)d_in[17];
    const float* br2 = (const float*)d_in[18];
    const float* We2 = (const float*)d_in[19];
    const float* att2= (const float*)d_in[20];
    const float* b2  = (const float*)d_in[21];
    const float* g2  = (const float*)d_in[22];
    const float* be2 = (const float*)d_in[23];
    const float* m2  = (const float*)d_in[24];
    const float* v2  = (const float*)d_in[25];
    const float* Wf1 = (const float*)d_in[26];
    const float* bf1 = (const float*)d_in[27];
    const float* Wf2 = (const float*)d_in[28];
    const float* bf2 = (const float*)d_in[29];
    float* out = (float*)d_out;

    // ---- workspace (~209.7 MB; proven >= 212.8 MB) ----
    const size_t XB  = (size_t)NN * 512 * 4;       // 102.4 MB panel
    const size_t HB  = (size_t)NN * 1024 * 2;      // 102.4 MB h1 bf16-hi
    const size_t WPB = (size_t)524288 * 2;         // 1 MB per split plane
    char* ws = (char*)d_ws;
    size_t off = 0;
    float* xlr  = (float*)(ws + off); off += XB;   // L1 panel; later xlr2 (L2 out)
    unsigned short* h1hi = (unsigned short*)(ws + off); off += HB;
    unsigned short* B1h = (unsigned short*)(ws + off); off += WPB;
    unsigned short* B1l = (unsigned short*)(ws + off); off += WPB;
    unsigned short* B2h = (unsigned short*)(ws + off); off += WPB;
    unsigned short* B2l = (unsigned short*)(ws + off); off += WPB;
    int* cnt    = (int*)(ws + off); off += (size_t)NN * 4;
    int* csroff = (int*)(ws + off); off += ((size_t)(NN + 1) * 4 + 15) & ~15ull;
    int* cursor = (int*)(ws + off); off += (size_t)NN * 4;
    int* eidl   = (int*)(ws + off); off += (size_t)NE * 4;
    if (ws_size < off) {
        fill_val<<<(out_size + 255) / 256, 256, 0, stream>>>(out, out_size, 1e30f);
        return;
    }
    float* xlr2 = xlr;   // alias: xlr dead after last node_fused<1>

    // ---- CSR build (once) ----
    hipMemsetAsync(cnt, 0, (size_t)NN * 4, stream);
    csr_count<<<(NE + 255) / 256, 256, 0, stream>>>(ei, cnt);
    csr_offsets<<<1, 1024, 0, stream>>>(cnt, csroff, cursor);
    csr_fill<<<(NE + 255) / 256, 256, 0, stream>>>(ei, cursor, eidl);

    // ---- weight prep ----
    wprep1t<<<2048, 256, 0, stream>>>(Wl1, Wr1, B1h, B1l);
    wprep2t<<<2048, 256, 0, stream>>>(Wl2, Wr2, B2h, B2l);

    // strip-clustered 1D grid: 196 strips -> pad to 200 (25 groups of 8) x 8 slices
    const int gemmBlocks = 25 * 64;   // 1600
    const int nodeBlocks = NN / 4;

    // ================= layer 1, per head =================
    for (int h = 0; h < NH; ++h) {
        gemm_bs<0><<<gemmBlocks, 256, 0, stream>>>(
            x, nullptr, 256, B1h + (size_t)h * 131072, B1l + (size_t)h * 131072, 8,
            bl1 + h * 256, br1 + h * 256, xlr, NN);
        node_fused<1, true><<<nodeBlocks, 256, 0, stream>>>(
            xlr, csroff, eidl, ei, ea, We1 + h * 256, 1024, att1 + h * 256,
            b1 + h * 256, g1 + h * 256, be1 + h * 256, m1 + h * 256, v1 + h * 256,
            h1hi, h * 256);
    }

    // ================= layer 2: single K=1024 GEMM =================
    gemm_bs<1><<<gemmBlocks, 256, 0, stream>>>(
        nullptr, h1hi, 1024, B2h, B2l, 32, bl2, br2, xlr2, NN);
    node_fused<4, false><<<nodeBlocks, 256, 0, stream>>>(
        xlr2, csroff, eidl, ei, ea, We2, 256, att2, b2, g2, be2, m2, v2,
        nullptr, 0);

    head_mlp<<<NG, 64, 0, stream>>>(xlr2, nnd, Wf1, bf1, Wf2, bf2, out);
}

// Round 11
// 1303.842 us; speedup vs baseline: 1.2559x; 1.2183x over previous
//
#include <hip/hip_runtime.h>
#include <math.h>

#define NN 50000
#define NE 200000
#define NH 4
#define NG 100
#define EPSBN 1e-5f
#define SLOPE 0.2f

typedef __attribute__((ext_vector_type(8))) short bf16x8;
typedef __attribute__((ext_vector_type(4))) float f32x4;

union U8 { bf16x8 v; uint4 q; unsigned w[4]; };

__device__ __forceinline__ unsigned short f2bf(float f) {
    unsigned u = __float_as_uint(f);
    unsigned r = (u + 0x7fffu + ((u >> 16) & 1u)) >> 16;   // RNE
    return (unsigned short)r;
}
__device__ __forceinline__ float bf2f(unsigned short s) {
    return __uint_as_float(((unsigned)s) << 16);
}

__global__ void fill_val(float* p, int n, float v) {
    int i = blockIdx.x * 256 + threadIdx.x;
    if (i < n) p[i] = v;
}

// ================= weight prep: fragment-tiled split panels (verbatim r9/r10) =================
__global__ void wprep1t(const float* __restrict__ Wl, const float* __restrict__ Wr,
                        unsigned short* __restrict__ Bh, unsigned short* __restrict__ Bl) {
    int idx = blockIdx.x * 256 + threadIdx.x;   // 524288
    int n = idx & 511, k = (idx >> 9) & 255, h = idx >> 17;
    const float* W = (n < 256) ? Wl : Wr;
    float w = W[(size_t)k * 1024 + h * 256 + (n & 255)];
    size_t dst = (size_t)h * 131072 + (((size_t)(n >> 4) * 8 + (k >> 5)) << 9)
               + ((((k >> 3) & 3) << 4) + (n & 15)) * 8 + (k & 7);
    unsigned u = __float_as_uint(w);
    Bh[dst] = (unsigned short)(u >> 16);                       // trunc hi
    Bl[dst] = f2bf(w - __uint_as_float(u & 0xFFFF0000u));      // RNE lo
}
__global__ void wprep2t(const float* __restrict__ Wl, const float* __restrict__ Wr,
                        unsigned short* __restrict__ Bh, unsigned short* __restrict__ Bl) {
    int idx = blockIdx.x * 256 + threadIdx.x;   // 524288
    int n = idx >> 10, k = idx & 1023;
    const float* W = (n < 256) ? Wl : Wr;
    float w = W[(size_t)k * 256 + (n & 255)];
    size_t dst = (((size_t)(n >> 4) * 32 + (k >> 5)) << 9)
               + ((((k >> 3) & 3) << 4) + (n & 15)) * 8 + (k & 7);
    unsigned u = __float_as_uint(w);
    Bh[dst] = (unsigned short)(u >> 16);
    Bl[dst] = f2bf(w - __uint_as_float(u & 0xFFFF0000u));
}

// ================= split-bf16 MFMA GEMM: 512-thr blocks, both B planes in LDS =================
// C[M,512] = A[M,K] @ B[512,K]^T + bias. Block = 512 thr = 8 waves, 512 rows x 64 cols;
// wave w: rows [m0+64w,+64) (4 m-frags) x 4 n-frags. Both B planes (64 KB) in LDS ->
// K-loop has NO global B on the critical path (r8's proven structure).
// 2 blocks/CU (LDS 128/160 KB) = 16 waves/CU; launch_bounds(512,2) keeps VGPR
// budget high (r9/r10's (256,4) starved the loader at 64 VGPR -> 275 us).
// Strip-clustered 1D grid (r10): p -> strip=((p>>6)<<3)+(p&7), slice=(p>>3)&7,
// so all 8 slices of a strip are dispatch-adjacent & same XCD -> A L2-shared.
// MODE 0: A f32 split in-reg, 3 passes, K=256. MODE 1: A bf16-hi, 2 passes, K=1024.
template<int MODE>
__launch_bounds__(512, 2)
__global__ void gemm_bs(const float* __restrict__ Af,
                        const unsigned short* __restrict__ A2, int lda,
                        const unsigned short* __restrict__ Bh,
                        const unsigned short* __restrict__ Bl, int KT,
                        const float* __restrict__ bL, const float* __restrict__ bR,
                        float* __restrict__ C, int M) {
    __shared__ unsigned short Bs[2][16384];   // 64 KB: [hi|lo][4nt x 8kt x 512]
    const int p = blockIdx.x;
    const int strip = ((p >> 6) << 3) + (p & 7);
    if (strip * 512 >= M) return;             // padded tail
    const int slice = (p >> 3) & 7;
    const int m0 = strip * 512;
    const int tid = threadIdx.x;
    const int lane = tid & 63, w = tid >> 6;
    const int r15 = lane & 15, kq = lane >> 4;
    const size_t sliceBase = (size_t)slice * 4 * KT * 64;   // uint4 units per plane

    f32x4 acc[4][4];
#pragma unroll
    for (int m = 0; m < 4; ++m)
#pragma unroll
        for (int n = 0; n < 4; ++n) acc[m][n] = (f32x4){0.f, 0.f, 0.f, 0.f};

    int rowm[4];
#pragma unroll
    for (int m = 0; m < 4; ++m) {
        int row = m0 + w * 64 + m * 16 + r15;
        rowm[m] = row < M ? row : M - 1;
    }

    const int nchunks = KT / 8;
    for (int kc = 0; kc < nchunks; ++kc) {
        // ---- fill both B planes for this 8-ktile chunk (4096 uint4, 512 thr) ----
        {
            const uint4* gh = (const uint4*)Bh + sliceBase;
            const uint4* gl = (const uint4*)Bl + sliceBase;
            uint4* lh = (uint4*)&Bs[0][0];
            uint4* ll = (uint4*)&Bs[1][0];
#pragma unroll
            for (int i = 0; i < 4; ++i) {
                int u = i * 512 + tid;
                int nt = u >> 9;
                int ktl = (u & 511) >> 6, j = u & 63;
                size_t gix = ((size_t)nt * KT + kc * 8 + ktl) * 64 + j;
                lh[u] = gh[gix];
                ll[u] = gl[gix];
            }
        }
        __syncthreads();

#pragma unroll
        for (int ktl = 0; ktl < 8; ++ktl) {
            const int kt = kc * 8 + ktl;
            bf16x8 ah[4], al[4];
            if (MODE == 0) {
#pragma unroll
                for (int m = 0; m < 4; ++m) {
                    const float* xp = Af + (size_t)rowm[m] * lda + kt * 32 + kq * 8;
                    float vv[8];
                    *(float4*)&vv[0] = *(const float4*)xp;
                    *(float4*)&vv[4] = *(const float4*)(xp + 4);
                    U8 uh, ul;
#pragma unroll
                    for (int j = 0; j < 4; ++j) {
                        float a0 = vv[2 * j], a1 = vv[2 * j + 1];
                        unsigned u0 = __float_as_uint(a0), u1 = __float_as_uint(a1);
                        uh.w[j] = (u0 >> 16) | (u1 & 0xFFFF0000u);
                        float l0 = a0 - __uint_as_float(u0 & 0xFFFF0000u);
                        float l1 = a1 - __uint_as_float(u1 & 0xFFFF0000u);
                        ul.w[j] = (unsigned)f2bf(l0) | ((unsigned)f2bf(l1) << 16);
                    }
                    ah[m] = uh.v; al[m] = ul.v;
                }
            } else {
#pragma unroll
                for (int m = 0; m < 4; ++m)
                    ah[m] = *(const bf16x8*)(A2 + (size_t)rowm[m] * lda + kt * 32 + kq * 8);
            }
#pragma unroll
            for (int n = 0; n < 4; ++n) {
                bf16x8 bh = *(const bf16x8*)&Bs[0][(n * 8 + ktl) * 512 + lane * 8];
                bf16x8 bl = *(const bf16x8*)&Bs[1][(n * 8 + ktl) * 512 + lane * 8];
#pragma unroll
                for (int m = 0; m < 4; ++m) {
                    acc[m][n] = __builtin_amdgcn_mfma_f32_16x16x32_bf16(
                        ah[m], bh, acc[m][n], 0, 0, 0);
                    if (MODE == 0)
                        acc[m][n] = __builtin_amdgcn_mfma_f32_16x16x32_bf16(
                            al[m], bh, acc[m][n], 0, 0, 0);
                    acc[m][n] = __builtin_amdgcn_mfma_f32_16x16x32_bf16(
                        ah[m], bl, acc[m][n], 0, 0, 0);
                }
            }
        }
        __syncthreads();
    }
    // ---- epilogue: C/D col=lane&15, row=(lane>>4)*4+reg (verified r4-r10) ----
#pragma unroll
    for (int n = 0; n < 4; ++n) {
        int gcol = slice * 64 + n * 16 + r15;
        float bv = (gcol < 256) ? bL[gcol] : bR[gcol - 256];
#pragma unroll
        for (int m = 0; m < 4; ++m) {
#pragma unroll
            for (int r = 0; r < 4; ++r) {
                int grow = m0 + w * 64 + m * 16 + kq * 4 + r;
                if (grow < M)
                    C[(size_t)grow * 512 + gcol] = acc[m][n][r] + bv;
            }
        }
    }
}

// ================= CSR build over dst (verified r5-r10) =================
__global__ void csr_count(const int* __restrict__ ei, int* __restrict__ cnt) {
    int e = blockIdx.x * 256 + threadIdx.x;
    if (e < NE) atomicAdd(&cnt[ei[NE + e]], 1);
}
__launch_bounds__(1024)
__global__ void csr_offsets(const int* __restrict__ cnt, int* __restrict__ off,
                            int* __restrict__ cursor) {
    __shared__ int s[1024];
    const int t = threadIdx.x;
    const int PER = 49;
    const int base = t * PER;
    int sum = 0;
    for (int i = 0; i < PER; ++i) {
        int idx = base + i;
        if (idx < NN) sum += cnt[idx];
    }
    s[t] = sum;
    __syncthreads();
    for (int d = 1; d < 1024; d <<= 1) {
        int v = (t >= d) ? s[t - d] : 0;
        __syncthreads();
        s[t] += v;
        __syncthreads();
    }
    int run = s[t] - sum;
    for (int i = 0; i < PER; ++i) {
        int idx = base + i;
        if (idx < NN) {
            off[idx] = run;
            cursor[idx] = run;
            run += cnt[idx];
            if (idx == NN - 1) off[NN] = run;
        }
    }
}
__global__ void csr_fill(const int* __restrict__ ei, int* __restrict__ cursor,
                         int* __restrict__ eidl) {
    int e = blockIdx.x * 256 + threadIdx.x;
    if (e < NE) {
        int d = ei[NE + e];
        int p = atomicAdd(&cursor[d], 1);
        eidl[p] = e;
    }
}

// ---------- per-edge logit partial (verbatim r6) ----------
__device__ __forceinline__ float edge_part(const float4& l, const float4& r,
                                           const float* ev, const float (*rW)[4],
                                           const float4& attv) {
    const float* lp = &l.x; const float* rp = &r.x; const float* ap = &attv.x;
    float part = 0.f;
#pragma unroll
    for (int j = 0; j < 4; ++j) {
        float ecf = 0.f;
#pragma unroll
        for (int d = 0; d < 12; ++d) ecf = fmaf(ev[d], rW[d][j], ecf);
        float mv = lp[j] + rp[j] + ecf;
        mv = mv > 0.f ? mv : SLOPE * mv;
        part = fmaf(mv, ap[j], part);
    }
    return part;
}

// ---------- fused node pass (verbatim r9/r10) ----------
template<int NHEADS, bool OUTHI>
__launch_bounds__(256)
__global__ void node_fused(float* __restrict__ xlr,
                           const int* __restrict__ off, const int* __restrict__ eidl,
                           const int* __restrict__ ei, const float* __restrict__ ea,
                           const float* __restrict__ We, int ldwe,
                           const float* __restrict__ att,
                           const float* __restrict__ bias, const float* __restrict__ gam,
                           const float* __restrict__ bet, const float* __restrict__ mu,
                           const float* __restrict__ var,
                           unsigned short* __restrict__ h1hi, int hcol) {
    const int n = blockIdx.x * 4 + (threadIdx.x >> 6);
    const int lane = threadIdx.x & 63;
    const int cf = lane * 4;
    float rW[12][4];
#pragma unroll
    for (int d = 0; d < 12; ++d) {
        float4 w = *(const float4*)&We[(size_t)d * ldwe + cf];
        rW[d][0] = w.x; rW[d][1] = w.y; rW[d][2] = w.z; rW[d][3] = w.w;
    }
    const float4 attv = *(const float4*)&att[cf];
    float* xrow = xlr + (size_t)n * 512;
    const float4 xr4 = *(const float4*)(xrow + 256 + cf);
    float acc[4] = {0.f, 0.f, 0.f, 0.f};
    float den = 0.f;
    const int beg = off[n], end = off[n + 1];
    constexpr int RED = 64 / NHEADS;
    int k = beg;
    for (; k + 2 <= end; k += 2) {
        int e0 = eidl[k], e1 = eidl[k + 1];
        int s0 = ei[e0], s1 = ei[e1];
        float ev0[12], ev1[12];
        const float2* p0 = (const float2*)(ea + (size_t)e0 * 12);
        const float2* p1 = (const float2*)(ea + (size_t)e1 * 12);
#pragma unroll
        for (int d = 0; d < 6; ++d) {
            float2 a = p0[d], b = p1[d];
            ev0[2 * d] = a.x; ev0[2 * d + 1] = a.y;
            ev1[2 * d] = b.x; ev1[2 * d + 1] = b.y;
        }
        float4 l0 = *(const float4*)(xlr + (size_t)s0 * 512 + cf);
        float4 l1 = *(const float4*)(xlr + (size_t)s1 * 512 + cf);
        float pa = edge_part(l0, xr4, ev0, rW, attv);
        float pb = edge_part(l1, xr4, ev1, rW, attv);
#pragma unroll
        for (int o = RED / 2; o > 0; o >>= 1) {
            pa += __shfl_xor(pa, o);
            pb += __shfl_xor(pb, o);
        }
        float ex0 = __expf(pa), ex1 = __expf(pb);
        den += ex0 + ex1;
        const float* lp0 = &l0.x; const float* lp1 = &l1.x;
#pragma unroll
        for (int j = 0; j < 4; ++j)
            acc[j] = fmaf(ex0, lp0[j], fmaf(ex1, lp1[j], acc[j]));
    }
    if (k < end) {
        int e0 = eidl[k];
        int s0 = ei[e0];
        float ev0[12];
        const float2* p0 = (const float2*)(ea + (size_t)e0 * 12);
#pragma unroll
        for (int d = 0; d < 6; ++d) {
            float2 a = p0[d];
            ev0[2 * d] = a.x; ev0[2 * d + 1] = a.y;
        }
        float4 l0 = *(const float4*)(xlr + (size_t)s0 * 512 + cf);
        float pa = edge_part(l0, xr4, ev0, rW, attv);
#pragma unroll
        for (int o = RED / 2; o > 0; o >>= 1) pa += __shfl_xor(pa, o);
        float ex0 = __expf(pa);
        den += ex0;
        const float* lp0 = &l0.x;
#pragma unroll
        for (int j = 0; j < 4; ++j) acc[j] = fmaf(ex0, lp0[j], acc[j]);
    }
    const float inv = 1.f / (den + 1e-16f);
    float o[4];
#pragma unroll
    for (int j = 0; j < 4; ++j) {
        int c = cf + j;
        float t = fmaxf(acc[j] * inv + bias[c], 0.f);
        o[j] = (t - mu[c]) * rsqrtf(var[c] + EPSBN) * gam[c] + bet[c];
    }
    if (OUTHI) {
        ushort4 hv;
        hv.x = f2bf(o[0]); hv.y = f2bf(o[1]); hv.z = f2bf(o[2]); hv.w = f2bf(o[3]);
        *(ushort4*)(h1hi + (size_t)n * 1024 + hcol + cf) = hv;
    } else {
        *(float4*)(xrow + 256 + cf) = make_float4(o[0], o[1], o[2], o[3]);
    }
}

// ================= head MLP =================
__launch_bounds__(64)
__global__ void head_mlp(const float* __restrict__ h2, const int* __restrict__ n_nodes,
                         const float* __restrict__ Wf1, const float* __restrict__ bf1,
                         const float* __restrict__ Wf2, const float* __restrict__ bf2,
                         float* __restrict__ out) {
    const int g = blockIdx.x;
    const int t = threadIdx.x;
    int acc = 0;
    for (int i = t; i <= g; i += 64) acc += n_nodes[i];
#pragma unroll
    for (int off = 32; off > 0; off >>= 1) acc += __shfl_xor(acc, off);
    const int node = acc - 1;
    __shared__ float row[256];
    for (int i = t; i < 256; i += 64) row[i] = h2[(size_t)node * 512 + 256 + i];
    __syncthreads();
    float hid = bf1[t];
    for (int k = 0; k < 256; ++k) hid = fmaf(row[k], Wf1[k * 64 + t], hid);
    hid = fmaxf(hid, 0.f);
    float p = hid * Wf2[t];
#pragma unroll
    for (int off = 32; off > 0; off >>= 1) p += __shfl_xor(p, off);
    if (t == 0) out[g] = p + bf2[0];
}

extern "C" void kernel_launch(void* const* d_in, const int* in_sizes, int n_in,
                              void* d_out, int out_size, void* d_ws, size_t ws_size,
                              hipStream_t stream) {
    const float* x   = (const float*)d_in[0];
    const int*   ei  = (const int*)d_in[1];
    const float* ea  = (const float*)d_in[2];
    const int*   nnd = (const int*)d_in[3];
    const float* Wl1 = (const float*)d_in[4];
    const float* bl1 = (const float*)d_in[5];
    const float* Wr1 = (const float*)d_in[6];
    const float* br1 = (const float*)d_in[7];
    const float* We1 = (const float*)d_in[8];
    const float* att1= (const float*)d_in[9];
    const float* b1  = (const float*)d_in[10];
    const float* g1  = (const float*)d_in[11];
    const float* be1 = (const float*)d_in[12];
    const float* m1  = (const float*)d_in[13];
    const float* v1  = (const float*)d_in[14];
    const float* Wl2 = (const float*)d_in[15];
    const float* bl2 = (const float*)d_in[16];
    const float* Wr2 = (const float*)d_in[17];
    const float* br2 = (const float*)d_in[18];
    const float* We2 = (const float*)d_in[19];
    const float* att2= (const float*)d_in[20];
    const float* b2  = (const float*)d_in[21];
    const float* g2  = (const float*)d_in[22];
    const float* be2 = (const float*)d_in[23];
    const float* m2  = (const float*)d_in[24];
    const float* v2  = (const float*)d_in[25];
    const float* Wf1 = (const float*)d_in[26];
    const float* bf1 = (const float*)d_in[27];
    const float* Wf2 = (const float*)d_in[28];
    const float* bf2 = (const float*)d_in[29];
    float* out = (float*)d_out;

    // ---- workspace (~209.7 MB; proven >= 212.8 MB) ----
    const size_t XB  = (size_t)NN * 512 * 4;       // 102.4 MB panel
    const size_t HB  = (size_t)NN * 1024 * 2;      // 102.4 MB h1 bf16-hi
    const size_t WPB = (size_t)524288 * 2;         // 1 MB per split plane
    char* ws = (char*)d_ws;
    size_t off = 0;
    float* xlr  = (float*)(ws + off); off += XB;   // L1 panel; later xlr2 (L2 out)
    unsigned short* h1hi = (unsigned short*)(ws + off); off += HB;
    unsigned short* B1h = (unsigned short*)(ws + off); off += WPB;
    unsigned short* B1l = (unsigned short*)(ws + off); off += WPB;
    unsigned short* B2h = (unsigned short*)(ws + off); off += WPB;
    unsigned short* B2l = (unsigned short*)(ws + off); off += WPB;
    int* cnt    = (int*)(ws + off); off += (size_t)NN * 4;
    int* csroff = (int*)(ws + off); off += ((size_t)(NN + 1) * 4 + 15) & ~15ull;
    int* cursor = (int*)(ws + off); off += (size_t)NN * 4;
    int* eidl   = (int*)(ws + off); off += (size_t)NE * 4;
    if (ws_size < off) {
        fill_val<<<(out_size + 255) / 256, 256, 0, stream>>>(out, out_size, 1e30f);
        return;
    }
    float* xlr2 = xlr;   // alias: xlr dead after last node_fused<1>

    // ---- CSR build (once) ----
    hipMemsetAsync(cnt, 0, (size_t)NN * 4, stream);
    csr_count<<<(NE + 255) / 256, 256, 0, stream>>>(ei, cnt);
    csr_offsets<<<1, 1024, 0, stream>>>(cnt, csroff, cursor);
    csr_fill<<<(NE + 255) / 256, 256, 0, stream>>>(ei, cursor, eidl);

    // ---- weight prep ----
    wprep1t<<<2048, 256, 0, stream>>>(Wl1, Wr1, B1h, B1l);
    wprep2t<<<2048, 256, 0, stream>>>(Wl2, Wr2, B2h, B2l);

    // strip-clustered 1D grid: 98 strips of 512 rows -> pad to 104 (13 groups of 8)
    const int gemmBlocks = 13 * 64;   // 832
    const int nodeBlocks = NN / 4;

    // ================= layer 1, per head =================
    for (int h = 0; h < NH; ++h) {
        gemm_bs<0><<<gemmBlocks, 512, 0, stream>>>(
            x, nullptr, 256, B1h + (size_t)h * 131072, B1l + (size_t)h * 131072, 8,
            bl1 + h * 256, br1 + h * 256, xlr, NN);
        node_fused<1, true><<<nodeBlocks, 256, 0, stream>>>(
            xlr, csroff, eidl, ei, ea, We1 + h * 256, 1024, att1 + h * 256,
            b1 + h * 256, g1 + h * 256, be1 + h * 256, m1 + h * 256, v1 + h * 256,
            h1hi, h * 256);
    }

    // ================= layer 2: single K=1024 GEMM =================
    gemm_bs<1><<<gemmBlocks, 512, 0, stream>>>(
        nullptr, h1hi, 1024, B2h, B2l, 32, bl2, br2, xlr2, NN);
    node_fused<4, false><<<nodeBlocks, 256, 0, stream>>>(
        xlr2, csroff, eidl, ei, ea, We2, 256, att2, b2, g2, be2, m2, v2,
        nullptr, 0);

    head_mlp<<<NG, 64, 0, stream>>>(xlr2, nnd, Wf1, bf1, Wf2, bf2, out);
}

// Round 12
// 1122.332 us; speedup vs baseline: 1.4591x; 1.1617x over previous
//
#include <hip/hip_runtime.h>
#include <math.h>

#define NN 50000
#define NE 200000
#define NH 4
#define NG 100
#define EPSBN 1e-5f
#define SLOPE 0.2f

typedef __attribute__((ext_vector_type(8))) short bf16x8;
typedef __attribute__((ext_vector_type(4))) float f32x4;

union U8 { bf16x8 v; uint4 q; unsigned w[4]; };

__device__ __forceinline__ unsigned short f2bf(float f) {
    unsigned u = __float_as_uint(f);
    unsigned r = (u + 0x7fffu + ((u >> 16) & 1u)) >> 16;   // RNE
    return (unsigned short)r;
}
__device__ __forceinline__ float bf2f(unsigned short s) {
    return __uint_as_float(((unsigned)s) << 16);
}

__global__ void fill_val(float* p, int n, float v) {
    int i = blockIdx.x * 256 + threadIdx.x;
    if (i < n) p[i] = v;
}

// ================= weight prep =================
// L1: trunc-hi + RNE-lo split (exact compensation), fragment-tiled.
__global__ void wprep1t(const float* __restrict__ Wl, const float* __restrict__ Wr,
                        unsigned short* __restrict__ Bh, unsigned short* __restrict__ Bl) {
    int idx = blockIdx.x * 256 + threadIdx.x;   // 524288
    int n = idx & 511, k = (idx >> 9) & 255, h = idx >> 17;
    const float* W = (n < 256) ? Wl : Wr;
    float w = W[(size_t)k * 1024 + h * 256 + (n & 255)];
    size_t dst = (size_t)h * 131072 + (((size_t)(n >> 4) * 8 + (k >> 5)) << 9)
               + ((((k >> 3) & 3) << 4) + (n & 15)) * 8 + (k & 7);
    unsigned u = __float_as_uint(w);
    Bh[dst] = (unsigned short)(u >> 16);                       // trunc hi
    Bl[dst] = f2bf(w - __uint_as_float(u & 0xFFFF0000u));      // RNE lo
}
// L2: RNE bf16 hi only (single-pass GEMM; h1 is already bf16-quantized so the
// B-side 2^-9 rel error adds a same-order term: predicted final ~4-6e-4 < 2.16e-3).
__global__ void wprep2t(const float* __restrict__ Wl, const float* __restrict__ Wr,
                        unsigned short* __restrict__ Bh) {
    int idx = blockIdx.x * 256 + threadIdx.x;   // 524288
    int n = idx >> 10, k = idx & 1023;
    const float* W = (n < 256) ? Wl : Wr;
    float w = W[(size_t)k * 256 + (n & 255)];
    size_t dst = (((size_t)(n >> 4) * 32 + (k >> 5)) << 9)
               + ((((k >> 3) & 3) << 4) + (n & 15)) * 8 + (k & 7);
    Bh[dst] = f2bf(w);
}

__device__ __forceinline__ void cvt_split(const float4& v0, const float4& v1,
                                          bf16x8& h, bf16x8& l) {
    float vv[8];
    *(float4*)&vv[0] = v0; *(float4*)&vv[4] = v1;
    U8 uh, ul;
#pragma unroll
    for (int j = 0; j < 4; ++j) {
        float a0 = vv[2 * j], a1 = vv[2 * j + 1];
        unsigned u0 = __float_as_uint(a0), u1 = __float_as_uint(a1);
        uh.w[j] = (u0 >> 16) | (u1 & 0xFFFF0000u);             // trunc hi pair
        float l0 = a0 - __uint_as_float(u0 & 0xFFFF0000u);
        float l1 = a1 - __uint_as_float(u1 & 0xFFFF0000u);
        ul.w[j] = (unsigned)f2bf(l0) | ((unsigned)f2bf(l1) << 16);
    }
    h = uh.v; l = ul.v;
}

// ================= split-bf16 MFMA GEMM, register-pipelined A =================
// Block = 512 thr = 8 waves; wave w owns rows [m0+32w,+32) (2 m-frags) x 4 n-frags
// (64 cols). acc = 32 AGPR -> VGPR headroom for explicit A double-buffer across
// K-steps (r11 post-mortem: 64 VGPR starved the loader; MfmaUtil 26%).
// MODE 0: A f32 split in-reg, 3 MFMA passes, K=256, both B planes in LDS (64 KB).
// MODE 1: A bf16-hi, 1 pass, K=1024, B-hi only in LDS (32 KB).
// Strip-clustered grid: p -> strip=((p>>6)<<3)+(p&7), slice=(p>>3)&7.
template<int MODE>
__launch_bounds__(512, 4)
__global__ void gemm_bs(const float* __restrict__ Af,
                        const unsigned short* __restrict__ A2, int lda,
                        const unsigned short* __restrict__ Bh,
                        const unsigned short* __restrict__ Bl, int KT,
                        const float* __restrict__ bL, const float* __restrict__ bR,
                        float* __restrict__ C, int M) {
    __shared__ unsigned short Bs[(MODE == 0 ? 2 : 1)][16384];
    const int p = blockIdx.x;
    const int strip = ((p >> 6) << 3) + (p & 7);
    if (strip * 256 >= M) return;             // padded tail
    const int slice = (p >> 3) & 7;
    const int m0 = strip * 256;
    const int tid = threadIdx.x;
    const int lane = tid & 63, w = tid >> 6;
    const int r15 = lane & 15, kq = lane >> 4;
    const size_t sliceBase = (size_t)slice * 4 * KT * 64;   // uint4 units/plane

    f32x4 acc[2][4];
#pragma unroll
    for (int m = 0; m < 2; ++m)
#pragma unroll
        for (int n = 0; n < 4; ++n) acc[m][n] = (f32x4){0.f, 0.f, 0.f, 0.f};

    const float* aPtr[2];
    const unsigned short* a2Ptr[2];
#pragma unroll
    for (int m = 0; m < 2; ++m) {
        int row = m0 + w * 32 + m * 16 + r15;
        row = row < M ? row : M - 1;
        if (MODE == 0) aPtr[m] = Af + (size_t)row * lda + kq * 8;
        else           a2Ptr[m] = A2 + (size_t)row * lda + kq * 8;
    }

    // ---- prime the A register pipeline (kt = 0) ----
    float4 curA[2][2];
    bf16x8 curH[2];
    if (MODE == 0) {
#pragma unroll
        for (int m = 0; m < 2; ++m) {
            curA[m][0] = *(const float4*)(aPtr[m]);
            curA[m][1] = *(const float4*)(aPtr[m] + 4);
        }
    } else {
#pragma unroll
        for (int m = 0; m < 2; ++m)
            curH[m] = *(const bf16x8*)(a2Ptr[m]);
    }

    const int nchunks = KT / 8;
    for (int kc = 0; kc < nchunks; ++kc) {
        // ---- fill B LDS for this 8-ktile chunk ----
        {
            const uint4* gh = (const uint4*)Bh + sliceBase;
            uint4* lh = (uint4*)&Bs[0][0];
#pragma unroll
            for (int i = 0; i < 4; ++i) {
                int u = i * 512 + tid;
                int nt = u >> 9;
                int ktl = (u & 511) >> 6, j = u & 63;
                size_t gix = ((size_t)nt * KT + kc * 8 + ktl) * 64 + j;
                lh[u] = gh[gix];
                if (MODE == 0)
                    ((uint4*)&Bs[1][0])[u] = ((const uint4*)Bl + sliceBase)[gix];
            }
        }
        __syncthreads();

#pragma unroll
        for (int ktl = 0; ktl < 8; ++ktl) {
            const int kt = kc * 8 + ktl;
            // ---- issue next-kt A loads before this kt's MFMA cluster ----
            float4 nxtA[2][2];
            bf16x8 nxtH[2];
            const bool hasNext = (kt + 1 < KT);
            if (hasNext) {
                if (MODE == 0) {
#pragma unroll
                    for (int m = 0; m < 2; ++m) {
                        nxtA[m][0] = *(const float4*)(aPtr[m] + (size_t)(kt + 1) * 32);
                        nxtA[m][1] = *(const float4*)(aPtr[m] + (size_t)(kt + 1) * 32 + 4);
                    }
                } else {
#pragma unroll
                    for (int m = 0; m < 2; ++m)
                        nxtH[m] = *(const bf16x8*)(a2Ptr[m] + (size_t)(kt + 1) * 32);
                }
            }
            // ---- convert current (MODE 0) ----
            bf16x8 ah[2], al[2];
            if (MODE == 0) {
#pragma unroll
                for (int m = 0; m < 2; ++m)
                    cvt_split(curA[m][0], curA[m][1], ah[m], al[m]);
            } else {
#pragma unroll
                for (int m = 0; m < 2; ++m) ah[m] = curH[m];
            }
            // ---- MFMA cluster ----
#pragma unroll
            for (int n = 0; n < 4; ++n) {
                bf16x8 bh = *(const bf16x8*)&Bs[0][(n * 8 + ktl) * 512 + lane * 8];
#pragma unroll
                for (int m = 0; m < 2; ++m)
                    acc[m][n] = __builtin_amdgcn_mfma_f32_16x16x32_bf16(
                        ah[m], bh, acc[m][n], 0, 0, 0);
                if (MODE == 0) {
                    bf16x8 bl = *(const bf16x8*)&Bs[1][(n * 8 + ktl) * 512 + lane * 8];
#pragma unroll
                    for (int m = 0; m < 2; ++m) {
                        acc[m][n] = __builtin_amdgcn_mfma_f32_16x16x32_bf16(
                            al[m], bh, acc[m][n], 0, 0, 0);
                        acc[m][n] = __builtin_amdgcn_mfma_f32_16x16x32_bf16(
                            ah[m], bl, acc[m][n], 0, 0, 0);
                    }
                }
            }
            // ---- rotate pipeline ----
            if (hasNext) {
                if (MODE == 0) {
#pragma unroll
                    for (int m = 0; m < 2; ++m) {
                        curA[m][0] = nxtA[m][0];
                        curA[m][1] = nxtA[m][1];
                    }
                } else {
#pragma unroll
                    for (int m = 0; m < 2; ++m) curH[m] = nxtH[m];
                }
            }
        }
        __syncthreads();
    }
    // ---- epilogue: C/D col=lane&15, row=(lane>>4)*4+reg (verified r4-r11) ----
#pragma unroll
    for (int n = 0; n < 4; ++n) {
        int gcol = slice * 64 + n * 16 + r15;
        float bv = (gcol < 256) ? bL[gcol] : bR[gcol - 256];
#pragma unroll
        for (int m = 0; m < 2; ++m) {
#pragma unroll
            for (int r = 0; r < 4; ++r) {
                int grow = m0 + w * 32 + m * 16 + kq * 4 + r;
                if (grow < M)
                    C[(size_t)grow * 512 + gcol] = acc[m][n][r] + bv;
            }
        }
    }
}

// ================= CSR build over dst (verified r5-r11) =================
__global__ void csr_count(const int* __restrict__ ei, int* __restrict__ cnt) {
    int e = blockIdx.x * 256 + threadIdx.x;
    if (e < NE) atomicAdd(&cnt[ei[NE + e]], 1);
}
__launch_bounds__(1024)
__global__ void csr_offsets(const int* __restrict__ cnt, int* __restrict__ off,
                            int* __restrict__ cursor) {
    __shared__ int s[1024];
    const int t = threadIdx.x;
    const int PER = 49;
    const int base = t * PER;
    int sum = 0;
    for (int i = 0; i < PER; ++i) {
        int idx = base + i;
        if (idx < NN) sum += cnt[idx];
    }
    s[t] = sum;
    __syncthreads();
    for (int d = 1; d < 1024; d <<= 1) {
        int v = (t >= d) ? s[t - d] : 0;
        __syncthreads();
        s[t] += v;
        __syncthreads();
    }
    int run = s[t] - sum;
    for (int i = 0; i < PER; ++i) {
        int idx = base + i;
        if (idx < NN) {
            off[idx] = run;
            cursor[idx] = run;
            run += cnt[idx];
            if (idx == NN - 1) off[NN] = run;
        }
    }
}
__global__ void csr_fill(const int* __restrict__ ei, int* __restrict__ cursor,
                         int* __restrict__ eidl) {
    int e = blockIdx.x * 256 + threadIdx.x;
    if (e < NE) {
        int d = ei[NE + e];
        int p = atomicAdd(&cursor[d], 1);
        eidl[p] = e;
    }
}

// ---------- per-edge logit partial (verbatim r6) ----------
__device__ __forceinline__ float edge_part(const float4& l, const float4& r,
                                           const float* ev, const float (*rW)[4],
                                           const float4& attv) {
    const float* lp = &l.x; const float* rp = &r.x; const float* ap = &attv.x;
    float part = 0.f;
#pragma unroll
    for (int j = 0; j < 4; ++j) {
        float ecf = 0.f;
#pragma unroll
        for (int d = 0; d < 12; ++d) ecf = fmaf(ev[d], rW[d][j], ecf);
        float mv = lp[j] + rp[j] + ecf;
        mv = mv > 0.f ? mv : SLOPE * mv;
        part = fmaf(mv, ap[j], part);
    }
    return part;
}

// ---------- fused node pass (verbatim r9-r11) ----------
template<int NHEADS, bool OUTHI>
__launch_bounds__(256)
__global__ void node_fused(float* __restrict__ xlr,
                           const int* __restrict__ off, const int* __restrict__ eidl,
                           const int* __restrict__ ei, const float* __restrict__ ea,
                           const float* __restrict__ We, int ldwe,
                           const float* __restrict__ att,
                           const float* __restrict__ bias, const float* __restrict__ gam,
                           const float* __restrict__ bet, const float* __restrict__ mu,
                           const float* __restrict__ var,
                           unsigned short* __restrict__ h1hi, int hcol) {
    const int n = blockIdx.x * 4 + (threadIdx.x >> 6);
    const int lane = threadIdx.x & 63;
    const int cf = lane * 4;
    float rW[12][4];
#pragma unroll
    for (int d = 0; d < 12; ++d) {
        float4 w = *(const float4*)&We[(size_t)d * ldwe + cf];
        rW[d][0] = w.x; rW[d][1] = w.y; rW[d][2] = w.z; rW[d][3] = w.w;
    }
    const float4 attv = *(const float4*)&att[cf];
    float* xrow = xlr + (size_t)n * 512;
    const float4 xr4 = *(const float4*)(xrow + 256 + cf);
    float acc[4] = {0.f, 0.f, 0.f, 0.f};
    float den = 0.f;
    const int beg = off[n], end = off[n + 1];
    constexpr int RED = 64 / NHEADS;
    int k = beg;
    for (; k + 2 <= end; k += 2) {
        int e0 = eidl[k], e1 = eidl[k + 1];
        int s0 = ei[e0], s1 = ei[e1];
        float ev0[12], ev1[12];
        const float2* p0 = (const float2*)(ea + (size_t)e0 * 12);
        const float2* p1 = (const float2*)(ea + (size_t)e1 * 12);
#pragma unroll
        for (int d = 0; d < 6; ++d) {
            float2 a = p0[d], b = p1[d];
            ev0[2 * d] = a.x; ev0[2 * d + 1] = a.y;
            ev1[2 * d] = b.x; ev1[2 * d + 1] = b.y;
        }
        float4 l0 = *(const float4*)(xlr + (size_t)s0 * 512 + cf);
        float4 l1 = *(const float4*)(xlr + (size_t)s1 * 512 + cf);
        float pa = edge_part(l0, xr4, ev0, rW, attv);
        float pb = edge_part(l1, xr4, ev1, rW, attv);
#pragma unroll
        for (int o = RED / 2; o > 0; o >>= 1) {
            pa += __shfl_xor(pa, o);
            pb += __shfl_xor(pb, o);
        }
        float ex0 = __expf(pa), ex1 = __expf(pb);
        den += ex0 + ex1;
        const float* lp0 = &l0.x; const float* lp1 = &l1.x;
#pragma unroll
        for (int j = 0; j < 4; ++j)
            acc[j] = fmaf(ex0, lp0[j], fmaf(ex1, lp1[j], acc[j]));
    }
    if (k < end) {
        int e0 = eidl[k];
        int s0 = ei[e0];
        float ev0[12];
        const float2* p0 = (const float2*)(ea + (size_t)e0 * 12);
#pragma unroll
        for (int d = 0; d < 6; ++d) {
            float2 a = p0[d];
            ev0[2 * d] = a.x; ev0[2 * d + 1] = a.y;
        }
        float4 l0 = *(const float4*)(xlr + (size_t)s0 * 512 + cf);
        float pa = edge_part(l0, xr4, ev0, rW, attv);
#pragma unroll
        for (int o = RED / 2; o > 0; o >>= 1) pa += __shfl_xor(pa, o);
        float ex0 = __expf(pa);
        den += ex0;
        const float* lp0 = &l0.x;
#pragma unroll
        for (int j = 0; j < 4; ++j) acc[j] = fmaf(ex0, lp0[j], acc[j]);
    }
    const float inv = 1.f / (den + 1e-16f);
    float o[4];
#pragma unroll
    for (int j = 0; j < 4; ++j) {
        int c = cf + j;
        float t = fmaxf(acc[j] * inv + bias[c], 0.f);
        o[j] = (t - mu[c]) * rsqrtf(var[c] + EPSBN) * gam[c] + bet[c];
    }
    if (OUTHI) {
        ushort4 hv;
        hv.x = f2bf(o[0]); hv.y = f2bf(o[1]); hv.z = f2bf(o[2]); hv.w = f2bf(o[3]);
        *(ushort4*)(h1hi + (size_t)n * 1024 + hcol + cf) = hv;
    } else {
        *(float4*)(xrow + 256 + cf) = make_float4(o[0], o[1], o[2], o[3]);
    }
}

// ================= head MLP =================
__launch_bounds__(64)
__global__ void head_mlp(const float* __restrict__ h2, const int* __restrict__ n_nodes,
                         const float* __restrict__ Wf1, const float* __restrict__ bf1,
                         const float* __restrict__ Wf2, const float* __restrict__ bf2,
                         float* __restrict__ out) {
    const int g = blockIdx.x;
    const int t = threadIdx.x;
    int acc = 0;
    for (int i = t; i <= g; i += 64) acc += n_nodes[i];
#pragma unroll
    for (int off = 32; off > 0; off >>= 1) acc += __shfl_xor(acc, off);
    const int node = acc - 1;
    __shared__ float row[256];
    for (int i = t; i < 256; i += 64) row[i] = h2[(size_t)node * 512 + 256 + i];
    __syncthreads();
    float hid = bf1[t];
    for (int k = 0; k < 256; ++k) hid = fmaf(row[k], Wf1[k * 64 + t], hid);
    hid = fmaxf(hid, 0.f);
    float p = hid * Wf2[t];
#pragma unroll
    for (int off = 32; off > 0; off >>= 1) p += __shfl_xor(p, off);
    if (t == 0) out[g] = p + bf2[0];
}

extern "C" void kernel_launch(void* const* d_in, const int* in_sizes, int n_in,
                              void* d_out, int out_size, void* d_ws, size_t ws_size,
                              hipStream_t stream) {
    const float* x   = (const float*)d_in[0];
    const int*   ei  = (const int*)d_in[1];
    const float* ea  = (const float*)d_in[2];
    const int*   nnd = (const int*)d_in[3];
    const float* Wl1 = (const float*)d_in[4];
    const float* bl1 = (const float*)d_in[5];
    const float* Wr1 = (const float*)d_in[6];
    const float* br1 = (const float*)d_in[7];
    const float* We1 = (const float*)d_in[8];
    const float* att1= (const float*)d_in[9];
    const float* b1  = (const float*)d_in[10];
    const float* g1  = (const float*)d_in[11];
    const float* be1 = (const float*)d_in[12];
    const float* m1  = (const float*)d_in[13];
    const float* v1  = (const float*)d_in[14];
    const float* Wl2 = (const float*)d_in[15];
    const float* bl2 = (const float*)d_in[16];
    const float* Wr2 = (const float*)d_in[17];
    const float* br2 = (const float*)d_in[18];
    const float* We2 = (const float*)d_in[19];
    const float* att2= (const float*)d_in[20];
    const float* b2  = (const float*)d_in[21];
    const float* g2  = (const float*)d_in[22];
    const float* be2 = (const float*)d_in[23];
    const float* m2  = (const float*)d_in[24];
    const float* v2  = (const float*)d_in[25];
    const float* Wf1 = (const float*)d_in[26];
    const float* bf1 = (const float*)d_in[27];
    const float* Wf2 = (const float*)d_in[28];
    const float* bf2 = (const float*)d_in[29];
    float* out = (float*)d_out;

    // ---- workspace (~208.7 MB; proven >= 212.8 MB) ----
    const size_t XB  = (size_t)NN * 512 * 4;       // 102.4 MB panel
    const size_t HB  = (size_t)NN * 1024 * 2;      // 102.4 MB h1 bf16-hi
    const size_t WPB = (size_t)524288 * 2;         // 1 MB per split plane
    char* ws = (char*)d_ws;
    size_t off = 0;
    float* xlr  = (float*)(ws + off); off += XB;   // L1 panel; later xlr2 (L2 out)
    unsigned short* h1hi = (unsigned short*)(ws + off); off += HB;
    unsigned short* B1h = (unsigned short*)(ws + off); off += WPB;
    unsigned short* B1l = (unsigned short*)(ws + off); off += WPB;
    unsigned short* B2h = (unsigned short*)(ws + off); off += WPB;
    int* cnt    = (int*)(ws + off); off += (size_t)NN * 4;
    int* csroff = (int*)(ws + off); off += ((size_t)(NN + 1) * 4 + 15) & ~15ull;
    int* cursor = (int*)(ws + off); off += (size_t)NN * 4;
    int* eidl   = (int*)(ws + off); off += (size_t)NE * 4;
    if (ws_size < off) {
        fill_val<<<(out_size + 255) / 256, 256, 0, stream>>>(out, out_size, 1e30f);
        return;
    }
    float* xlr2 = xlr;   // alias: xlr dead after last node_fused<1>

    // ---- CSR build (once) ----
    hipMemsetAsync(cnt, 0, (size_t)NN * 4, stream);
    csr_count<<<(NE + 255) / 256, 256, 0, stream>>>(ei, cnt);
    csr_offsets<<<1, 1024, 0, stream>>>(cnt, csroff, cursor);
    csr_fill<<<(NE + 255) / 256, 256, 0, stream>>>(ei, cursor, eidl);

    // ---- weight prep ----
    wprep1t<<<2048, 256, 0, stream>>>(Wl1, Wr1, B1h, B1l);
    wprep2t<<<2048, 256, 0, stream>>>(Wl2, Wr2, B2h);

    // strip-clustered 1D grid: 196 strips of 256 rows -> pad to 200 (25 groups of 8)
    const int gemmBlocks = 25 * 64;   // 1600
    const int nodeBlocks = NN / 4;

    // ================= layer 1, per head =================
    for (int h = 0; h < NH; ++h) {
        gemm_bs<0><<<gemmBlocks, 512, 0, stream>>>(
            x, nullptr, 256, B1h + (size_t)h * 131072, B1l + (size_t)h * 131072, 8,
            bl1 + h * 256, br1 + h * 256, xlr, NN);
        node_fused<1, true><<<nodeBlocks, 256, 0, stream>>>(
            xlr, csroff, eidl, ei, ea, We1 + h * 256, 1024, att1 + h * 256,
            b1 + h * 256, g1 + h * 256, be1 + h * 256, m1 + h * 256, v1 + h * 256,
            h1hi, h * 256);
    }

    // ================= layer 2: single K=1024, single-pass GEMM =================
    gemm_bs<1><<<gemmBlocks, 512, 0, stream>>>(
        nullptr, h1hi, 1024, B2h, nullptr, 32, bl2, br2, xlr2, NN);
    node_fused<4, false><<<nodeBlocks, 256, 0, stream>>>(
        xlr2, csroff, eidl, ei, ea, We2, 256, att2, b2, g2, be2, m2, v2,
        nullptr, 0);

    head_mlp<<<NG, 64, 0, stream>>>(xlr2, nnd, Wf1, bf1, Wf2, bf2, out);
}